// Round 10
// baseline (15.563 us; speedup 1.0000x reference)
//
#include <hip/hip_runtime.h>

// StructuredPerceptron: B=32, S=2048, T=512
// loss = sum_b max(pred_score_b - gold_score_b, 0)
// score_b = sum_{s<L} unary[b,s,tag[s]] + sum_{1<=s<L} binary[tag[s-1],tag[s]]
// L = sum_s mask[b,s]
//
// R4 structure (best known, 11.05us): 32 blocks x 256 thr, single node,
// coalesced prefetch -> barrier-reduced L -> predicated gathers -> counter
// finish. This round ONLY shrinks load-issue count: contiguous-per-thread
// mapping (thread owns s = tid*8..tid*8+7) turns 40 scalar loads/thread
// into 6 int4 loads; shifted tag/pred streams are derived in-register
// (tg[k-1] within thread, __shfl_up across lanes, 3 scalar fixups/block
// at wave boundaries). Bytes unchanged, request count ~7x lower.

#define BB 32
#define SS 2048
#define TT 512

__device__ int sp_counter = 0;  // invariant: ==0 whenever no kernel in flight

__global__ __launch_bounds__(256) void sp_fused_kernel(
    const float* __restrict__ unary,
    const float* __restrict__ binary,
    const int*   __restrict__ tags,
    const int*   __restrict__ pred,
    const int*   __restrict__ mask,
    float*       __restrict__ ws,
    float*       __restrict__ out)
{
    const int b    = blockIdx.x;
    const int tid  = threadIdx.x;
    const int wave = tid >> 6;
    const int lane = tid & 63;

    __shared__ int   s_ipart[4];
    __shared__ float s_part[8];
    __shared__ int   s_len;

    const int s0   = tid * 8;          // this thread's 8 contiguous positions
    const int base = b * SS + s0;      // 32B-aligned -> int4-clean

    // ---- 1. vectorized prefetch: 2 int4 per stream ----
    const int4* tgp = reinterpret_cast<const int4*>(&tags[base]);
    const int4* tpp = reinterpret_cast<const int4*>(&pred[base]);
    const int4* mp  = reinterpret_cast<const int4*>(&mask[base]);
    const int4 tgA = tgp[0], tgB = tgp[1];
    const int4 tpA = tpp[0], tpB = tpp[1];
    const int4 mA  = mp[0],  mB  = mp[1];

    const int tg[8] = {tgA.x, tgA.y, tgA.z, tgA.w, tgB.x, tgB.y, tgB.z, tgB.w};
    const int tp[8] = {tpA.x, tpA.y, tpA.z, tpA.w, tpB.x, tpB.y, tpB.z, tpB.w};

    // shifted streams in-register: lane l needs lane l-1's tg[7]/tp[7]
    int prev_tg = __shfl_up(tg[7], 1);
    int prev_tp = __shfl_up(tp[7], 1);
    if (lane == 0 && s0 >= 1) {        // wave boundary: 3 threads/block
        prev_tg = tags[base - 1];
        prev_tp = pred[base - 1];
    }

    // ---- 2. L = sum(mask[b,:]) — R4 barrier reduce ----
    int m = mA.x + mA.y + mA.z + mA.w + mB.x + mB.y + mB.z + mB.w;
    #pragma unroll
    for (int off = 32; off > 0; off >>= 1) m += __shfl_down(m, off);
    if (lane == 0) s_ipart[wave] = m;
    __syncthreads();
    if (tid == 0) s_len = s_ipart[0] + s_ipart[1] + s_ipart[2] + s_ipart[3];
    __syncthreads();
    const int L = s_len;

    // ---- 3. predicated scattered gathers ----
    float g = 0.f, p = 0.f;
    #pragma unroll
    for (int k = 0; k < 8; ++k) {
        const int s = s0 + k;
        if (s < L) {
            g += unary[(base + k) * TT + tg[k]];
            p += unary[(base + k) * TT + tp[k]];
            if (s >= 1) {
                const int t0 = k ? tg[k - 1] : prev_tg;
                const int q0 = k ? tp[k - 1] : prev_tp;
                g += binary[t0 * TT + tg[k]];
                p += binary[q0 * TT + tp[k]];
            }
        }
    }

    // ---- 4. block reduce ----
    #pragma unroll
    for (int off = 32; off > 0; off >>= 1) {
        g += __shfl_down(g, off);
        p += __shfl_down(p, off);
    }
    if (lane == 0) { s_part[wave * 2] = g; s_part[wave * 2 + 1] = p; }
    __syncthreads();

    // ---- 5. publish + last-block finish ----
    if (tid == 0) {
        const float G = s_part[0] + s_part[2] + s_part[4] + s_part[6];
        const float P = s_part[1] + s_part[3] + s_part[5] + s_part[7];
        ws[2 * b]     = G;
        ws[2 * b + 1] = P;
        __threadfence();                        // publish ws before arrival
        const int old = atomicAdd(&sp_counter, 1);
        if (old == BB - 1) {                    // last block: finish
            __threadfence();                    // acquire all ws writes
            float total = 0.f;
            for (int i = 0; i < BB; ++i) {      // fixed order -> deterministic
                const float Gi = ws[2 * i];
                const float Pi = ws[2 * i + 1];
                total += fmaxf(Pi - Gi, 0.f);
            }
            out[0] = total;
            atomicExch(&sp_counter, 0);         // restore invariant for replay
        }
    }
}

extern "C" void kernel_launch(void* const* d_in, const int* in_sizes, int n_in,
                              void* d_out, int out_size, void* d_ws, size_t ws_size,
                              hipStream_t stream) {
    const float* unary  = (const float*)d_in[0];
    const float* binary = (const float*)d_in[1];
    const int*   tags   = (const int*)d_in[2];
    const int*   pred   = (const int*)d_in[3];
    const int*   mask   = (const int*)d_in[4];
    float* ws  = (float*)d_ws;
    float* out = (float*)d_out;

    sp_fused_kernel<<<BB, 256, 0, stream>>>(unary, binary, tags, pred, mask, ws, out);
}

// Round 11
// 13.350 us; speedup vs baseline: 1.1657x; 1.1657x over previous
//
#include <hip/hip_runtime.h>

// StructuredPerceptron: B=32, S=2048, T=512
// loss = sum_b max(pred_score_b - gold_score_b, 0)
// score_b = sum_{s<L} unary[b,s,tag[s]] + sum_{1<=s<L} binary[tag[s-1],tag[s]]
// L = sum_s mask[b,s]
//
// FINAL (= R4, best measured 11.05us). 32 blocks x 256 thr, single graph
// node. Strided per-thread mapping (s = tid + k*256) keeps each wave's
// gather cloud in a contiguous 128KB window (R10 lesson: locality of the
// wave's address cloud >> instruction count). Coalesced prefetch of
// mask/tags/preds overlaps the L-reduce with in-flight loads; scattered
// unary/binary gathers are predicated by s<L (R5 lesson: extra gathers
// cost ~+5.7us); 32-way counter finish (R6 lesson: 256-way sync costs
// ~+3us; R1vR3: second kernel node is free but unnecessary here).

#define BB 32
#define SS 2048
#define TT 512

__device__ int sp_counter = 0;  // invariant: ==0 whenever no kernel in flight

__global__ __launch_bounds__(256) void sp_fused_kernel(
    const float* __restrict__ unary,
    const float* __restrict__ binary,
    const int*   __restrict__ tags,
    const int*   __restrict__ pred,
    const int*   __restrict__ mask,
    float*       __restrict__ ws,
    float*       __restrict__ out)
{
    const int b    = blockIdx.x;
    const int tid  = threadIdx.x;
    const int wave = tid >> 6;

    __shared__ int   s_ipart[4];
    __shared__ float s_part[8];
    __shared__ int   s_len;

    // ---- 1. prefetch ALL coalesced streams up front (independent of L) ----
    int mk[8], tg[8], tp[8], tg0[8], tp0[8];
    #pragma unroll
    for (int k = 0; k < 8; ++k) {
        const int s    = tid + k * 256;
        const int base = b * SS + s;
        mk[k]  = mask[base];
        tg[k]  = tags[base];
        tp[k]  = pred[base];
        tg0[k] = (s >= 1) ? tags[base - 1] : 0;
        tp0[k] = (s >= 1) ? pred[base - 1] : 0;
    }

    // ---- 2. seq_len reduce (overlaps the in-flight tag/pred loads) ----
    int m = 0;
    #pragma unroll
    for (int k = 0; k < 8; ++k) m += mk[k];
    #pragma unroll
    for (int off = 32; off > 0; off >>= 1) m += __shfl_down(m, off);
    if ((tid & 63) == 0) s_ipart[wave] = m;
    __syncthreads();
    if (tid == 0) s_len = s_ipart[0] + s_ipart[1] + s_ipart[2] + s_ipart[3];
    __syncthreads();
    const int L = s_len;

    // ---- 3. predicated scattered gathers (tags already in registers) ----
    float g = 0.f, p = 0.f;
    #pragma unroll
    for (int k = 0; k < 8; ++k) {
        const int s    = tid + k * 256;
        const int base = b * SS + s;
        if (s < L) {
            g += unary[base * TT + tg[k]];
            p += unary[base * TT + tp[k]];
            if (s >= 1) {
                g += binary[tg0[k] * TT + tg[k]];
                p += binary[tp0[k] * TT + tp[k]];
            }
        }
    }
    #pragma unroll
    for (int off = 32; off > 0; off >>= 1) {
        g += __shfl_down(g, off);
        p += __shfl_down(p, off);
    }
    if ((tid & 63) == 0) { s_part[wave * 2] = g; s_part[wave * 2 + 1] = p; }
    __syncthreads();

    // ---- 4. publish + last-block finish ----
    if (tid == 0) {
        const float G = s_part[0] + s_part[2] + s_part[4] + s_part[6];
        const float P = s_part[1] + s_part[3] + s_part[5] + s_part[7];
        ws[2 * b]     = G;
        ws[2 * b + 1] = P;
        __threadfence();                        // publish ws before arrival
        const int old = atomicAdd(&sp_counter, 1);
        if (old == BB - 1) {                    // last block: finish
            __threadfence();                    // acquire all ws writes
            float total = 0.f;
            for (int i = 0; i < BB; ++i) {      // fixed order -> deterministic
                const float Gi = ws[2 * i];
                const float Pi = ws[2 * i + 1];
                total += fmaxf(Pi - Gi, 0.f);
            }
            out[0] = total;
            atomicExch(&sp_counter, 0);         // restore invariant for replay
        }
    }
}

extern "C" void kernel_launch(void* const* d_in, const int* in_sizes, int n_in,
                              void* d_out, int out_size, void* d_ws, size_t ws_size,
                              hipStream_t stream) {
    const float* unary  = (const float*)d_in[0];
    const float* binary = (const float*)d_in[1];
    const int*   tags   = (const int*)d_in[2];
    const int*   pred   = (const int*)d_in[3];
    const int*   mask   = (const int*)d_in[4];
    float* ws  = (float*)d_ws;
    float* out = (float*)d_out;

    sp_fused_kernel<<<BB, 256, 0, stream>>>(unary, binary, tags, pred, mask, ws, out);
}